// Round 7
// baseline (242.599 us; speedup 1.0000x reference)
//
#include <hip/hip_runtime.h>
#include <hip/hip_bf16.h>

#define N_NODES 100000
#define N_EDGES 600000
#define CH 128
#define N_GRAPHS 100
#define BN_EPS 1e-5f
#define NBUCKET 32
#define CAP 16               // per-node edge slab = exactly 1 cache line (64B)
#define OVFCAP 8192          // overflow list (deg>16 nodes; ~15 for Poisson(6))
#define EDGE_BLOCKS 2344     // ceil(N_EDGES/256), 1 edge/thread for max MLP
#define GEMM_BLOCKS 1563     // ceil(N_NODES/64)
#define GATHER_BLOCKS 2048
#define BN_BLOCKS 1563       // ceil(N_NODES/64)
#define ZERO_INTS (N_NODES + 2 * NBUCKET * CH + 4)   // 108196
#define ZERO_BLOCKS 423
#define PHIS_BLOCKS 50       // N_GRAPHS*CH/256
#define WT_BLOCKS 64

typedef __bf16 bf16x8 __attribute__((ext_vector_type(8)));
typedef float f32x4 __attribute__((ext_vector_type(4)));

__device__ __forceinline__ ushort f2bf(float f) {
    union { float f; unsigned u; } x; x.f = f;
    unsigned u = x.u;
    unsigned r = (u + 0x7fffu + ((u >> 16) & 1u)) >> 16;
    return (ushort)r;
}
__device__ __forceinline__ float bflo(unsigned p) { return __builtin_bit_cast(float, p << 16); }
__device__ __forceinline__ float bfhi(unsigned p) { return __builtin_bit_cast(float, p & 0xffff0000u); }

// ---------------------------------------------------------------------------
// k_prep: zero cnt/psum/psq/ovfcur, zero phis, build Wt = bf16(W^T).
// ---------------------------------------------------------------------------
__global__ __launch_bounds__(256) void k_prep(const float* __restrict__ W,
        int* __restrict__ zbase, ushort* __restrict__ Wt, float* __restrict__ phis) {
    unsigned bid = blockIdx.x;
    int tid = threadIdx.x;
    if (bid < ZERO_BLOCKS) {
        int i = bid * 256 + tid;
        if (i < ZERO_INTS) zbase[i] = 0;
    } else if (bid < ZERO_BLOCKS + PHIS_BLOCKS) {
        int i = (bid - ZERO_BLOCKS) * 256 + tid;
        phis[i] = 0.f;
    } else {
        int t = (bid - ZERO_BLOCKS - PHIS_BLOCKS) * 256 + tid;  // 16384
        int k = t >> 7, o = t & 127;
        Wt[o * CH + k] = f2bf(W[t]);
    }
}

// ---------------------------------------------------------------------------
// k_fill: 1 edge/thread, minimal VGPR, nontemporal esrc scatter.
// ---------------------------------------------------------------------------
__global__ __launch_bounds__(256) void k_fill(const int* __restrict__ src,
        const int* __restrict__ dst, int* __restrict__ cnt,
        int* __restrict__ ovfcur, int* __restrict__ ovf, int* __restrict__ esrc) {
    int e = blockIdx.x * 256 + threadIdx.x;
    if (e < N_EDGES) {
        int d = dst[e], s = src[e];
        int slot = atomicAdd(&cnt[d], 1);
        if (slot < CAP) __builtin_nontemporal_store(s, &esrc[d * CAP + slot]);
        else { int p = atomicAdd(ovfcur, 1); if (p < OVFCAP) { ovf[2*p] = d; ovf[2*p+1] = s; } }
    }
}

// ---------------------------------------------------------------------------
// k_zgemm: z16 = bf16((h @ W) .* norm)  [linearity: nm*(h@W) == (nm*h)@W]
// Transposed mfma (verified r3/r5/r6). All 8 h-float4 loads hoisted and
// independent; norm decoupled from the load->convert chain; scale applied
// post-MFMA in f32. Target: ~40 outstanding loads/SIMD instead of ~2/wave.
// ---------------------------------------------------------------------------
__global__ __launch_bounds__(256) void k_zgemm(const float* __restrict__ h,
        const float* __restrict__ norm, const ushort* __restrict__ Wt,
        ushort* __restrict__ z16) {
    int tid = threadIdx.x;
    int w = tid >> 6, L = tid & 63;
    int c15 = L & 15, quad = L >> 4;
    int n0 = blockIdx.x * 64 + w * 16 + c15;
    bool v0 = n0 < N_NODES;
    int nr = v0 ? n0 : 0;                       // safe row for OOB lanes
    const float* h0 = h + (size_t)nr * CH;
    float nm0 = v0 ? norm[n0] : 0.f;            // independent of h loads

    // ---- 8 independent 16B loads, all issued before any use ----
    float4 hv[8];
    #pragma unroll
    for (int i = 0; i < 8; i++)
        hv[i] = *(const float4*)(h0 + (i >> 1) * 32 + quad * 8 + (i & 1) * 4);

    // ---- convert (no norm scaling here) ----
    bf16x8 bfr[4];
    #pragma unroll
    for (int kt = 0; kt < 4; kt++) {
        union { bf16x8 v; ushort u[8]; } r;
        float4 p = hv[2 * kt], q = hv[2 * kt + 1];
        r.u[0] = f2bf(p.x); r.u[1] = f2bf(p.y);
        r.u[2] = f2bf(p.z); r.u[3] = f2bf(p.w);
        r.u[4] = f2bf(q.x); r.u[5] = f2bf(q.y);
        r.u[6] = f2bf(q.z); r.u[7] = f2bf(q.w);
        bfr[kt] = r.v;
    }

    f32x4 acc[8] = {};
    #pragma unroll
    for (int kt = 0; kt < 4; kt++) {
        int k = kt * 32 + quad * 8;
        #pragma unroll
        for (int ot = 0; ot < 8; ot++) {
            bf16x8 a = *(const bf16x8*)(Wt + (size_t)(ot * 16 + c15) * CH + k);
            acc[ot] = __builtin_amdgcn_mfma_f32_16x16x32_bf16(a, bfr[kt], acc[ot], 0, 0, 0);
        }
    }

    if (v0) {
        ushort* zr = z16 + (size_t)n0 * CH;
        #pragma unroll
        for (int ot = 0; ot < 8; ot++) {
            float z0 = acc[ot][0] * nm0, z1 = acc[ot][1] * nm0;
            float z2 = acc[ot][2] * nm0, z3 = acc[ot][3] * nm0;
            uint2 dv;
            dv.x = (unsigned)f2bf(z0) | ((unsigned)f2bf(z1) << 16);
            dv.y = (unsigned)f2bf(z2) | ((unsigned)f2bf(z3) << 16);
            *(uint2*)(zr + ot * 16 + quad * 4) = dv;
        }
    }
}

// ---------------------------------------------------------------------------
// k_gather: grid-stride over nodes; 16 lanes/node, 8 ch/lane. (verified r6)
// ---------------------------------------------------------------------------
__global__ __launch_bounds__(256) void k_gather(const ushort* __restrict__ z16,
        const float* __restrict__ norm, const int* __restrict__ cnt,
        const int* __restrict__ esrc, const int* __restrict__ ovfcur,
        const int* __restrict__ ovf, const float* __restrict__ bias,
        ushort* __restrict__ y16, float* __restrict__ psum, float* __restrict__ psq) {
    __shared__ float sred[2][16][CH];   // 16 KB

    int tid = threadIdx.x;
    int cg = tid & 15, rl = tid >> 4;
    int c = cg * 8;
    float4 b0 = *(const float4*)(bias + c), b1 = *(const float4*)(bias + c + 4);
    float s8[8] = {}, q8[8] = {};
    int no = min(*ovfcur, OVFCAP);

    for (int n = blockIdx.x * 16 + rl; n < N_NODES; n += GATHER_BLOCKS * 16) {
        int craw = cnt[n];
        int e = min(craw, CAP);
        float nn = norm[n];
        int base = n * CAP;
        float a0=0.f,a1=0.f,a2=0.f,a3=0.f,a4=0.f,a5=0.f,a6=0.f,a7=0.f;
        int j = 0;
        for (; j + 4 <= e; j += 4) {
            int4 s4 = *(const int4*)(esrc + base + j);
            uint4 v0 = *(const uint4*)(z16 + (size_t)s4.x * CH + c);
            uint4 v1 = *(const uint4*)(z16 + (size_t)s4.y * CH + c);
            uint4 v2 = *(const uint4*)(z16 + (size_t)s4.z * CH + c);
            uint4 v3 = *(const uint4*)(z16 + (size_t)s4.w * CH + c);
            a0 += bflo(v0.x) + bflo(v1.x) + bflo(v2.x) + bflo(v3.x);
            a1 += bfhi(v0.x) + bfhi(v1.x) + bfhi(v2.x) + bfhi(v3.x);
            a2 += bflo(v0.y) + bflo(v1.y) + bflo(v2.y) + bflo(v3.y);
            a3 += bfhi(v0.y) + bfhi(v1.y) + bfhi(v2.y) + bfhi(v3.y);
            a4 += bflo(v0.z) + bflo(v1.z) + bflo(v2.z) + bflo(v3.z);
            a5 += bfhi(v0.z) + bfhi(v1.z) + bfhi(v2.z) + bfhi(v3.z);
            a6 += bflo(v0.w) + bflo(v1.w) + bflo(v2.w) + bflo(v3.w);
            a7 += bfhi(v0.w) + bfhi(v1.w) + bfhi(v2.w) + bfhi(v3.w);
        }
        for (; j < e; j++) {
            int s = esrc[base + j];
            uint4 v = *(const uint4*)(z16 + (size_t)s * CH + c);
            a0 += bflo(v.x); a1 += bfhi(v.x);
            a2 += bflo(v.y); a3 += bfhi(v.y);
            a4 += bflo(v.z); a5 += bfhi(v.z);
            a6 += bflo(v.w); a7 += bfhi(v.w);
        }
        if (craw > CAP && no > 0) {     // gate: only overflowed nodes scan
            for (int i = 0; i < no; i++) {
                if (ovf[2*i] == n) {
                    int s = ovf[2*i+1];
                    uint4 v = *(const uint4*)(z16 + (size_t)s * CH + c);
                    a0 += bflo(v.x); a1 += bfhi(v.x);
                    a2 += bflo(v.y); a3 += bfhi(v.y);
                    a4 += bflo(v.z); a5 += bfhi(v.z);
                    a6 += bflo(v.w); a7 += bfhi(v.w);
                }
            }
        }
        float f[8];
        f[0] = fmaxf(fmaf(a0, nn, b0.x), 0.f);
        f[1] = fmaxf(fmaf(a1, nn, b0.y), 0.f);
        f[2] = fmaxf(fmaf(a2, nn, b0.z), 0.f);
        f[3] = fmaxf(fmaf(a3, nn, b0.w), 0.f);
        f[4] = fmaxf(fmaf(a4, nn, b1.x), 0.f);
        f[5] = fmaxf(fmaf(a5, nn, b1.y), 0.f);
        f[6] = fmaxf(fmaf(a6, nn, b1.z), 0.f);
        f[7] = fmaxf(fmaf(a7, nn, b1.w), 0.f);
        uint4 o;
        o.x = (unsigned)f2bf(f[0]) | ((unsigned)f2bf(f[1]) << 16);
        o.y = (unsigned)f2bf(f[2]) | ((unsigned)f2bf(f[3]) << 16);
        o.z = (unsigned)f2bf(f[4]) | ((unsigned)f2bf(f[5]) << 16);
        o.w = (unsigned)f2bf(f[6]) | ((unsigned)f2bf(f[7]) << 16);
        *(uint4*)(y16 + (size_t)n * CH + c) = o;
        #pragma unroll
        for (int k = 0; k < 8; k++) { s8[k] += f[k]; q8[k] += f[k] * f[k]; }
    }

    *(float4*)&sred[0][rl][c]     = make_float4(s8[0], s8[1], s8[2], s8[3]);
    *(float4*)&sred[0][rl][c + 4] = make_float4(s8[4], s8[5], s8[6], s8[7]);
    *(float4*)&sred[1][rl][c]     = make_float4(q8[0], q8[1], q8[2], q8[3]);
    *(float4*)&sred[1][rl][c + 4] = make_float4(q8[4], q8[5], q8[6], q8[7]);
    __syncthreads();
    if (tid < 128) {
        float S = 0.f, Q = 0.f;
        #pragma unroll
        for (int k = 0; k < 16; k++) { S += sred[0][k][tid]; Q += sred[1][k][tid]; }
        int bucket = blockIdx.x & (NBUCKET - 1);
        atomicAdd(&psum[bucket * CH + tid], S);
        atomicAdd(&psq[bucket * CH + tid], Q);
    }
}

// ---------------------------------------------------------------------------
// k_finalize: ONE block reduces the 32 buckets -> scale/shift. Removes the
// per-block redundant reduce (was ~50 MB of L2 reads across 1563 blocks).
// ---------------------------------------------------------------------------
__global__ void k_finalize(const float* __restrict__ psum, const float* __restrict__ psq,
        const float* __restrict__ gamma, const float* __restrict__ beta,
        float* __restrict__ scale, float* __restrict__ shift) {
    int t = threadIdx.x;   // 128
    float S = 0.f, Q = 0.f;
    #pragma unroll
    for (int g = 0; g < NBUCKET; g++) { S += psum[g * CH + t]; Q += psq[g * CH + t]; }
    const float invN = 1.f / (float)N_NODES;
    float mean = S * invN;
    float var  = Q * invN - mean * mean;
    float sc   = gamma[t] * rsqrtf(var + BN_EPS);
    scale[t] = sc;
    shift[t] = beta[t] - mean * sc;
}

// ---------------------------------------------------------------------------
// k_bnpool: BN apply (bf16 y16 -> f32 x) + per-graph pooling. 64 rows/block.
// scale/shift read from global (256 floats, L2-hot).
// ---------------------------------------------------------------------------
__global__ __launch_bounds__(256) void k_bnpool(const ushort* __restrict__ y16,
        const int* __restrict__ gids, const float* __restrict__ scale,
        const float* __restrict__ shift, float* __restrict__ xout,
        float* __restrict__ phis) {
    __shared__ float smP[16][CH];   // 8 KB

    int tid = threadIdx.x;
    int cg = tid & 15, rl = tid >> 4;
    int c = cg * 8;
    int r0 = blockIdx.x * 64;
    int rbase = r0 + rl * 4;

    float4 sc0 = *(const float4*)(scale + c), sc1 = *(const float4*)(scale + c + 4);
    float4 sh0 = *(const float4*)(shift + c), sh1 = *(const float4*)(shift + c + 4);

    bool fast = (r0 + 63 < N_NODES) && (gids[r0] == gids[r0 + 63]);

    if (fast) {
        float4 p0 = make_float4(0.f,0.f,0.f,0.f), p1 = make_float4(0.f,0.f,0.f,0.f);
        #pragma unroll
        for (int j = 0; j < 4; j++) {
            int r = rbase + j;
            uint4 v = *(const uint4*)(y16 + (size_t)r * CH + c);
            float4 f0, f1;
            f0.x = fmaf(bflo(v.x), sc0.x, sh0.x); f0.y = fmaf(bfhi(v.x), sc0.y, sh0.y);
            f0.z = fmaf(bflo(v.y), sc0.z, sh0.z); f0.w = fmaf(bfhi(v.y), sc0.w, sh0.w);
            f1.x = fmaf(bflo(v.z), sc1.x, sh1.x); f1.y = fmaf(bfhi(v.z), sc1.y, sh1.y);
            f1.z = fmaf(bflo(v.w), sc1.z, sh1.z); f1.w = fmaf(bfhi(v.w), sc1.w, sh1.w);
            *(float4*)(xout + (size_t)r * CH + c) = f0;
            *(float4*)(xout + (size_t)r * CH + c + 4) = f1;
            p0.x += f0.x; p0.y += f0.y; p0.z += f0.z; p0.w += f0.w;
            p1.x += f1.x; p1.y += f1.y; p1.z += f1.z; p1.w += f1.w;
        }
        *(float4*)&smP[rl][c] = p0;
        *(float4*)&smP[rl][c + 4] = p1;
        __syncthreads();
        if (tid < 128) {
            int g = gids[r0];
            float S = 0.f;
            #pragma unroll
            for (int k = 0; k < 16; k++) S += smP[k][tid];
            atomicAdd(&phis[(size_t)g * CH + tid], S);
        }
    } else {
        float p[8] = {};
        int gprev = -1;
        #pragma unroll
        for (int j = 0; j < 4; j++) {
            int r = rbase + j;
            if (r >= N_NODES) break;
            int g = gids[r];
            if (g != gprev) {
                if (gprev >= 0) {
                    #pragma unroll
                    for (int k = 0; k < 8; k++) {
                        atomicAdd(&phis[(size_t)gprev * CH + c + k], p[k]);
                        p[k] = 0.f;
                    }
                }
                gprev = g;
            }
            uint4 v = *(const uint4*)(y16 + (size_t)r * CH + c);
            float f[8];
            f[0] = fmaf(bflo(v.x), sc0.x, sh0.x); f[1] = fmaf(bfhi(v.x), sc0.y, sh0.y);
            f[2] = fmaf(bflo(v.y), sc0.z, sh0.z); f[3] = fmaf(bfhi(v.y), sc0.w, sh0.w);
            f[4] = fmaf(bflo(v.z), sc1.x, sh1.x); f[5] = fmaf(bfhi(v.z), sc1.y, sh1.y);
            f[6] = fmaf(bflo(v.w), sc1.z, sh1.z); f[7] = fmaf(bfhi(v.w), sc1.w, sh1.w);
            *(float4*)(xout + (size_t)r * CH + c) = make_float4(f[0], f[1], f[2], f[3]);
            *(float4*)(xout + (size_t)r * CH + c + 4) = make_float4(f[4], f[5], f[6], f[7]);
            #pragma unroll
            for (int k = 0; k < 8; k++) p[k] += f[k];
        }
        if (gprev >= 0) {
            #pragma unroll
            for (int k = 0; k < 8; k++)
                atomicAdd(&phis[(size_t)gprev * CH + c + k], p[k]);
        }
    }
}

// ---------------------------------------------------------------------------
extern "C" void kernel_launch(void* const* d_in, const int* in_sizes, int n_in,
                              void* d_out, int out_size, void* d_ws, size_t ws_size,
                              hipStream_t stream)
{
    const float* h     = (const float*)d_in[0];
    const float* norm  = (const float*)d_in[1];
    const float* W     = (const float*)d_in[2];
    const float* b     = (const float*)d_in[3];
    const float* gamma = (const float*)d_in[4];
    const float* beta  = (const float*)d_in[5];
    const int*   src   = (const int*)d_in[6];
    const int*   dst   = (const int*)d_in[7];
    const int*   gids  = (const int*)d_in[8];

    float* x_out = (float*)d_out;                       // [N,128]
    float* phis  = x_out + (size_t)N_NODES * CH;        // [100,128]

    ushort* z16  = (ushort*)d_ws;                       // [N,128] bf16 (h@W)*norm
    ushort* y16  = z16 + (size_t)N_NODES * CH;          // [N,128] bf16 relu(...)
    ushort* Wt   = y16 + (size_t)N_NODES * CH;          // [128,128] bf16 W^T
    // ---- zeroed region (k_prep) ----
    int*   cnt     = (int*)(Wt + CH * CH);              // [N] per-node edge count
    float* psum    = (float*)(cnt + N_NODES);           // [32,128]
    float* psq     = psum + NBUCKET * CH;               // [32,128]
    int*   ovfcur  = (int*)(psq + NBUCKET * CH);        // [4]
    // ---- end zeroed region ----
    int*   esrc    = ovfcur + 4;                        // [N*CAP] slabs (1 line/node)
    int*   ovf     = esrc + (size_t)N_NODES * CAP;      // [2*OVFCAP] (dst,src) pairs
    float* scale   = (float*)(ovf + 2 * OVFCAP);        // [128]
    float* shift   = scale + CH;                        // [128]

    k_prep<<<ZERO_BLOCKS + PHIS_BLOCKS + WT_BLOCKS, 256, 0, stream>>>(W, cnt, Wt, phis);
    k_fill<<<EDGE_BLOCKS, 256, 0, stream>>>(src, dst, cnt, ovfcur, ovf, esrc);
    k_zgemm<<<GEMM_BLOCKS, 256, 0, stream>>>(h, norm, Wt, z16);
    k_gather<<<GATHER_BLOCKS, 256, 0, stream>>>(
        z16, norm, cnt, esrc, ovfcur, ovf, b, y16, psum, psq);
    k_finalize<<<1, 128, 0, stream>>>(psum, psq, gamma, beta, scale, shift);
    k_bnpool<<<BN_BLOCKS, 256, 0, stream>>>(
        y16, gids, scale, shift, x_out, phis);
}

// Round 8
// 230.648 us; speedup vs baseline: 1.0518x; 1.0518x over previous
//
#include <hip/hip_runtime.h>
#include <hip/hip_bf16.h>

#define N_NODES 100000
#define N_PAD 100096         // 782 * 128
#define N_EDGES 600000
#define CH 128
#define N_GRAPHS 100
#define BN_EPS 1e-5f
#define NBUCKET 32
#define CAP 16               // per-node edge slab = exactly 1 cache line (64B)
#define OVFCAP 8192          // overflow list (deg>16 nodes; ~15 for Poisson(6))
#define EDGE_BLOCKS 2344     // ceil(N_EDGES/256)
#define GEMM_BLOCKS 782      // N_PAD/128
#define GATHER_BLOCKS 2048
#define BN_BLOCKS 1563       // ceil(N_NODES/64)
#define ZERO_INTS (N_NODES + 2 * NBUCKET * CH + 4)   // 108196
#define ZERO_BLOCKS 423
#define PHIS_BLOCKS 50       // N_GRAPHS*CH/256
#define WT_BLOCKS 64
#define PRESCALE_BLOCKS 6250 // N_NODES*16/256

typedef __bf16 bf16x8 __attribute__((ext_vector_type(8)));
typedef float f32x4 __attribute__((ext_vector_type(4)));

__device__ __forceinline__ ushort f2bf(float f) {
    union { float f; unsigned u; } x; x.f = f;
    unsigned u = x.u;
    unsigned r = (u + 0x7fffu + ((u >> 16) & 1u)) >> 16;
    return (ushort)r;
}
__device__ __forceinline__ float bflo(unsigned p) { return __builtin_bit_cast(float, p << 16); }
__device__ __forceinline__ float bfhi(unsigned p) { return __builtin_bit_cast(float, p & 0xffff0000u); }

// ---------------------------------------------------------------------------
// k_prep: zero cnt/psum/psq/ovfcur, zero phis, build Wt = bf16(W^T),
// AND prescale xh = bf16(h .* norm)  (streaming BW job; f32 h is read HERE,
// in a latency-insensitive kernel, so the GEMM later reads warm bf16).
// ---------------------------------------------------------------------------
__global__ __launch_bounds__(256) void k_prep(const float* __restrict__ W,
        const float* __restrict__ h, const float* __restrict__ norm,
        int* __restrict__ zbase, ushort* __restrict__ Wt,
        float* __restrict__ phis, ushort* __restrict__ xh) {
    unsigned bid = blockIdx.x;
    int tid = threadIdx.x;
    if (bid < ZERO_BLOCKS) {
        int i = bid * 256 + tid;
        if (i < ZERO_INTS) zbase[i] = 0;
    } else if (bid < ZERO_BLOCKS + PHIS_BLOCKS) {
        int i = (bid - ZERO_BLOCKS) * 256 + tid;
        phis[i] = 0.f;
    } else if (bid < ZERO_BLOCKS + PHIS_BLOCKS + WT_BLOCKS) {
        int t = (bid - ZERO_BLOCKS - PHIS_BLOCKS) * 256 + tid;  // 16384
        int k = t >> 7, o = t & 127;
        Wt[o * CH + k] = f2bf(W[t]);
    } else {
        int t = (bid - ZERO_BLOCKS - PHIS_BLOCKS - WT_BLOCKS) * 256 + tid; // N*16
        int n = t >> 4, c = (t & 15) << 3;
        float nm = norm[n];
        float4 a = *(const float4*)(h + (size_t)n * CH + c);
        float4 d = *(const float4*)(h + (size_t)n * CH + c + 4);
        uint4 o;
        o.x = (unsigned)f2bf(a.x * nm) | ((unsigned)f2bf(a.y * nm) << 16);
        o.y = (unsigned)f2bf(a.z * nm) | ((unsigned)f2bf(a.w * nm) << 16);
        o.z = (unsigned)f2bf(d.x * nm) | ((unsigned)f2bf(d.y * nm) << 16);
        o.w = (unsigned)f2bf(d.z * nm) | ((unsigned)f2bf(d.w * nm) << 16);
        *(uint4*)(xh + (size_t)n * CH + c) = o;
    }
}

// ---------------------------------------------------------------------------
// k_fill: 1 edge/thread, minimal VGPR, nontemporal esrc scatter.
// ---------------------------------------------------------------------------
__global__ __launch_bounds__(256) void k_fill(const int* __restrict__ src,
        const int* __restrict__ dst, int* __restrict__ cnt,
        int* __restrict__ ovfcur, int* __restrict__ ovf, int* __restrict__ esrc) {
    int e = blockIdx.x * 256 + threadIdx.x;
    if (e < N_EDGES) {
        int d = dst[e], s = src[e];
        int slot = atomicAdd(&cnt[d], 1);
        if (slot < CAP) __builtin_nontemporal_store(s, &esrc[d * CAP + slot]);
        else { int p = atomicAdd(ovfcur, 1); if (p < OVFCAP) { ovf[2*p] = d; ovf[2*p+1] = s; } }
    }
}

// ---------------------------------------------------------------------------
// k_gather: grid-stride over nodes; 16 lanes/node, 8 ch/lane.
// x2[n] = bf16( (sum xh[src]) * norm[n] );  pad rows [N,N_PAD) zeroed.
// No stats here (they moved to k_gemm's epilogue).
// ---------------------------------------------------------------------------
__global__ __launch_bounds__(256) void k_gather(const ushort* __restrict__ xh,
        const float* __restrict__ norm, const int* __restrict__ cnt,
        const int* __restrict__ esrc, const int* __restrict__ ovfcur,
        const int* __restrict__ ovf, ushort* __restrict__ x2) {
    int tid = threadIdx.x;
    int cg = tid & 15, rl = tid >> 4;
    int c = cg * 8;
    int no = min(*ovfcur, OVFCAP);

    for (int n = blockIdx.x * 16 + rl; n < N_PAD; n += GATHER_BLOCKS * 16) {
        if (n >= N_NODES) {
            uint4 z = {0u, 0u, 0u, 0u};
            *(uint4*)(x2 + (size_t)n * CH + c) = z;
            continue;
        }
        int craw = cnt[n];
        int e = min(craw, CAP);
        float nn = norm[n];
        int base = n * CAP;
        float a0=0.f,a1=0.f,a2=0.f,a3=0.f,a4=0.f,a5=0.f,a6=0.f,a7=0.f;
        int j = 0;
        for (; j + 4 <= e; j += 4) {
            int4 s4 = *(const int4*)(esrc + base + j);
            uint4 v0 = *(const uint4*)(xh + (size_t)s4.x * CH + c);
            uint4 v1 = *(const uint4*)(xh + (size_t)s4.y * CH + c);
            uint4 v2 = *(const uint4*)(xh + (size_t)s4.z * CH + c);
            uint4 v3 = *(const uint4*)(xh + (size_t)s4.w * CH + c);
            a0 += bflo(v0.x) + bflo(v1.x) + bflo(v2.x) + bflo(v3.x);
            a1 += bfhi(v0.x) + bfhi(v1.x) + bfhi(v2.x) + bfhi(v3.x);
            a2 += bflo(v0.y) + bflo(v1.y) + bflo(v2.y) + bflo(v3.y);
            a3 += bfhi(v0.y) + bfhi(v1.y) + bfhi(v2.y) + bfhi(v3.y);
            a4 += bflo(v0.z) + bflo(v1.z) + bflo(v2.z) + bflo(v3.z);
            a5 += bfhi(v0.z) + bfhi(v1.z) + bfhi(v2.z) + bfhi(v3.z);
            a6 += bflo(v0.w) + bflo(v1.w) + bflo(v2.w) + bflo(v3.w);
            a7 += bfhi(v0.w) + bfhi(v1.w) + bfhi(v2.w) + bfhi(v3.w);
        }
        for (; j < e; j++) {
            int s = esrc[base + j];
            uint4 v = *(const uint4*)(xh + (size_t)s * CH + c);
            a0 += bflo(v.x); a1 += bfhi(v.x);
            a2 += bflo(v.y); a3 += bfhi(v.y);
            a4 += bflo(v.z); a5 += bfhi(v.z);
            a6 += bflo(v.w); a7 += bfhi(v.w);
        }
        if (craw > CAP && no > 0) {
            for (int i = 0; i < no; i++) {
                if (ovf[2*i] == n) {
                    int s = ovf[2*i+1];
                    uint4 v = *(const uint4*)(xh + (size_t)s * CH + c);
                    a0 += bflo(v.x); a1 += bfhi(v.x);
                    a2 += bflo(v.y); a3 += bfhi(v.y);
                    a4 += bflo(v.z); a5 += bfhi(v.z);
                    a6 += bflo(v.w); a7 += bfhi(v.w);
                }
            }
        }
        uint4 o;
        o.x = (unsigned)f2bf(a0 * nn) | ((unsigned)f2bf(a1 * nn) << 16);
        o.y = (unsigned)f2bf(a2 * nn) | ((unsigned)f2bf(a3 * nn) << 16);
        o.z = (unsigned)f2bf(a4 * nn) | ((unsigned)f2bf(a5 * nn) << 16);
        o.w = (unsigned)f2bf(a6 * nn) | ((unsigned)f2bf(a7 * nn) << 16);
        *(uint4*)(x2 + (size_t)n * CH + c) = o;
    }
}

// ---------------------------------------------------------------------------
// k_gemm (round-0 verified design): 128 rows/block, wave = two 16-row tiles.
// y16 = bf16(relu(x2@W + b)) via LDS-staged coalesced stores + BN stats.
// bf16 input (25.6 MB, cache-warm) — the GEMM variant that measured fast.
// ---------------------------------------------------------------------------
__global__ __launch_bounds__(256) void k_gemm(const ushort* __restrict__ x2,
        const ushort* __restrict__ Wt, const float* __restrict__ bias,
        ushort* __restrict__ y16, float* __restrict__ psum, float* __restrict__ psq) {
    __shared__ ushort ys[128 * CH];   // 32 KB; reused as float[4096] for stats

    int tid = threadIdx.x;
    int w = tid >> 6, L = tid & 63;
    int c15 = L & 15, quad = L >> 4;
    size_t nb = (size_t)blockIdx.x * 128 + w * 32;

    const bf16x8* A0 = (const bf16x8*)(x2 + (nb + c15) * CH);
    const bf16x8* A1 = (const bf16x8*)(x2 + (nb + 16 + c15) * CH);

    f32x4 acc0[8] = {}, acc1[8] = {};
    #pragma unroll
    for (int kt = 0; kt < 4; kt++) {
        bf16x8 a0 = A0[kt * 4 + quad];
        bf16x8 a1 = A1[kt * 4 + quad];
        #pragma unroll
        for (int ot = 0; ot < 8; ot++) {
            bf16x8 b = *(const bf16x8*)(Wt + (size_t)(ot * 16 + c15) * CH + kt * 32 + quad * 8);
            acc0[ot] = __builtin_amdgcn_mfma_f32_16x16x32_bf16(a0, b, acc0[ot], 0, 0, 0);
            acc1[ot] = __builtin_amdgcn_mfma_f32_16x16x32_bf16(a1, b, acc1[ot], 0, 0, 0);
        }
    }

    float sA[8], qA[8];
    #pragma unroll
    for (int ot = 0; ot < 8; ot++) {
        int col = ot * 16 + c15;
        float bv = bias[col];
        float s_ = 0.f, q_ = 0.f;
        #pragma unroll
        for (int r = 0; r < 4; r++) {
            size_t n = nb + quad * 4 + r;
            float v = fmaxf(acc0[ot][r] + bv, 0.f);
            ys[(w * 32 + quad * 4 + r) * CH + col] = f2bf(v);
            if (n < N_NODES) { s_ += v; q_ += v * v; }
            size_t n2 = n + 16;
            float v2 = fmaxf(acc1[ot][r] + bv, 0.f);
            ys[(w * 32 + 16 + quad * 4 + r) * CH + col] = f2bf(v2);
            if (n2 < N_NODES) { s_ += v2; q_ += v2 * v2; }
        }
        sA[ot] = s_; qA[ot] = q_;
    }
    __syncthreads();

    // cooperative coalesced y16 store: 2048 uint4, 8 per thread
    {
        const uint4* ysv = (const uint4*)ys;
        uint4* out = (uint4*)(y16 + (size_t)blockIdx.x * 128 * CH);
        #pragma unroll
        for (int i = 0; i < 8; i++) out[tid + i * 256] = ysv[tid + i * 256];
    }
    __syncthreads();

    // stats reduction (reuse ys as float buffer: 2048 S + 2048 Q)
    float* red = (float*)ys;
    #pragma unroll
    for (int ot = 0; ot < 8; ot++) {
        red[ot * 256 + tid] = sA[ot];
        red[2048 + ot * 256 + tid] = qA[ot];
    }
    __syncthreads();

    if (tid < 128) {
        int ot = tid >> 4, cc = tid & 15;
        int col = ot * 16 + cc;
        float S = 0.f, Q = 0.f;
        #pragma unroll
        for (int g = 0; g < 16; g++) {
            int sl = (g >> 2) * 64 + (g & 3) * 16 + cc;
            S += red[ot * 256 + sl];
            Q += red[2048 + ot * 256 + sl];
        }
        int bucket = blockIdx.x & (NBUCKET - 1);
        atomicAdd(&psum[bucket * CH + col], S);
        atomicAdd(&psq[bucket * CH + col], Q);
    }
}

// ---------------------------------------------------------------------------
// k_finalize: ONE block reduces the buckets -> scale/shift.
// ---------------------------------------------------------------------------
__global__ void k_finalize(const float* __restrict__ psum, const float* __restrict__ psq,
        const float* __restrict__ gamma, const float* __restrict__ beta,
        float* __restrict__ scale, float* __restrict__ shift) {
    int t = threadIdx.x;   // 128
    float S = 0.f, Q = 0.f;
    #pragma unroll
    for (int g = 0; g < NBUCKET; g++) { S += psum[g * CH + t]; Q += psq[g * CH + t]; }
    const float invN = 1.f / (float)N_NODES;
    float mean = S * invN;
    float var  = Q * invN - mean * mean;
    float sc   = gamma[t] * rsqrtf(var + BN_EPS);
    scale[t] = sc;
    shift[t] = beta[t] - mean * sc;
}

// ---------------------------------------------------------------------------
// k_bnpool: BN apply (bf16 y16 -> f32 x) + per-graph pooling. 64 rows/block.
// ---------------------------------------------------------------------------
__global__ __launch_bounds__(256) void k_bnpool(const ushort* __restrict__ y16,
        const int* __restrict__ gids, const float* __restrict__ scale,
        const float* __restrict__ shift, float* __restrict__ xout,
        float* __restrict__ phis) {
    __shared__ float smP[16][CH];   // 8 KB

    int tid = threadIdx.x;
    int cg = tid & 15, rl = tid >> 4;
    int c = cg * 8;
    int r0 = blockIdx.x * 64;
    int rbase = r0 + rl * 4;

    float4 sc0 = *(const float4*)(scale + c), sc1 = *(const float4*)(scale + c + 4);
    float4 sh0 = *(const float4*)(shift + c), sh1 = *(const float4*)(shift + c + 4);

    bool fast = (r0 + 63 < N_NODES) && (gids[r0] == gids[r0 + 63]);

    if (fast) {
        float4 p0 = make_float4(0.f,0.f,0.f,0.f), p1 = make_float4(0.f,0.f,0.f,0.f);
        #pragma unroll
        for (int j = 0; j < 4; j++) {
            int r = rbase + j;
            uint4 v = *(const uint4*)(y16 + (size_t)r * CH + c);
            float4 f0, f1;
            f0.x = fmaf(bflo(v.x), sc0.x, sh0.x); f0.y = fmaf(bfhi(v.x), sc0.y, sh0.y);
            f0.z = fmaf(bflo(v.y), sc0.z, sh0.z); f0.w = fmaf(bfhi(v.y), sc0.w, sh0.w);
            f1.x = fmaf(bflo(v.z), sc1.x, sh1.x); f1.y = fmaf(bfhi(v.z), sc1.y, sh1.y);
            f1.z = fmaf(bflo(v.w), sc1.z, sh1.z); f1.w = fmaf(bfhi(v.w), sc1.w, sh1.w);
            *(float4*)(xout + (size_t)r * CH + c) = f0;
            *(float4*)(xout + (size_t)r * CH + c + 4) = f1;
            p0.x += f0.x; p0.y += f0.y; p0.z += f0.z; p0.w += f0.w;
            p1.x += f1.x; p1.y += f1.y; p1.z += f1.z; p1.w += f1.w;
        }
        *(float4*)&smP[rl][c] = p0;
        *(float4*)&smP[rl][c + 4] = p1;
        __syncthreads();
        if (tid < 128) {
            int g = gids[r0];
            float S = 0.f;
            #pragma unroll
            for (int k = 0; k < 16; k++) S += smP[k][tid];
            atomicAdd(&phis[(size_t)g * CH + tid], S);
        }
    } else {
        float p[8] = {};
        int gprev = -1;
        #pragma unroll
        for (int j = 0; j < 4; j++) {
            int r = rbase + j;
            if (r >= N_NODES) break;
            int g = gids[r];
            if (g != gprev) {
                if (gprev >= 0) {
                    #pragma unroll
                    for (int k = 0; k < 8; k++) {
                        atomicAdd(&phis[(size_t)gprev * CH + c + k], p[k]);
                        p[k] = 0.f;
                    }
                }
                gprev = g;
            }
            uint4 v = *(const uint4*)(y16 + (size_t)r * CH + c);
            float f[8];
            f[0] = fmaf(bflo(v.x), sc0.x, sh0.x); f[1] = fmaf(bfhi(v.x), sc0.y, sh0.y);
            f[2] = fmaf(bflo(v.y), sc0.z, sh0.z); f[3] = fmaf(bfhi(v.y), sc0.w, sh0.w);
            f[4] = fmaf(bflo(v.z), sc1.x, sh1.x); f[5] = fmaf(bfhi(v.z), sc1.y, sh1.y);
            f[6] = fmaf(bflo(v.w), sc1.z, sh1.z); f[7] = fmaf(bfhi(v.w), sc1.w, sh1.w);
            *(float4*)(xout + (size_t)r * CH + c) = make_float4(f[0], f[1], f[2], f[3]);
            *(float4*)(xout + (size_t)r * CH + c + 4) = make_float4(f[4], f[5], f[6], f[7]);
            #pragma unroll
            for (int k = 0; k < 8; k++) p[k] += f[k];
        }
        if (gprev >= 0) {
            #pragma unroll
            for (int k = 0; k < 8; k++)
                atomicAdd(&phis[(size_t)gprev * CH + c + k], p[k]);
        }
    }
}

// ---------------------------------------------------------------------------
extern "C" void kernel_launch(void* const* d_in, const int* in_sizes, int n_in,
                              void* d_out, int out_size, void* d_ws, size_t ws_size,
                              hipStream_t stream)
{
    const float* h     = (const float*)d_in[0];
    const float* norm  = (const float*)d_in[1];
    const float* W     = (const float*)d_in[2];
    const float* b     = (const float*)d_in[3];
    const float* gamma = (const float*)d_in[4];
    const float* beta  = (const float*)d_in[5];
    const int*   src   = (const int*)d_in[6];
    const int*   dst   = (const int*)d_in[7];
    const int*   gids  = (const int*)d_in[8];

    float* x_out = (float*)d_out;                       // [N,128]
    float* phis  = x_out + (size_t)N_NODES * CH;        // [100,128]

    ushort* xh   = (ushort*)d_ws;                       // [N,128] bf16 h*norm
    ushort* x2   = xh + (size_t)N_NODES * CH;           // [N_PAD,128] bf16 agg*norm
    ushort* y16  = x2 + (size_t)N_PAD * CH;             // [N_PAD,128] bf16 relu(..)
    ushort* Wt   = y16 + (size_t)N_PAD * CH;            // [128,128] bf16 W^T
    // ---- zeroed region (k_prep) ----
    int*   cnt     = (int*)(Wt + CH * CH);              // [N]
    float* psum    = (float*)(cnt + N_NODES);           // [32,128]
    float* psq     = psum + NBUCKET * CH;               // [32,128]
    int*   ovfcur  = (int*)(psq + NBUCKET * CH);        // [4]
    // ---- end zeroed region ----
    int*   esrc    = ovfcur + 4;                        // [N*CAP]
    int*   ovf     = esrc + (size_t)N_NODES * CAP;      // [2*OVFCAP]
    float* scale   = (float*)(ovf + 2 * OVFCAP);        // [128]
    float* shift   = scale + CH;                        // [128]

    k_prep<<<ZERO_BLOCKS + PHIS_BLOCKS + WT_BLOCKS + PRESCALE_BLOCKS, 256, 0, stream>>>(
        W, h, norm, cnt, Wt, phis, xh);
    k_fill<<<EDGE_BLOCKS, 256, 0, stream>>>(src, dst, cnt, ovfcur, ovf, esrc);
    k_gather<<<GATHER_BLOCKS, 256, 0, stream>>>(
        xh, norm, cnt, esrc, ovfcur, ovf, x2);
    k_gemm<<<GEMM_BLOCKS, 256, 0, stream>>>(x2, Wt, b, y16, psum, psq);
    k_finalize<<<1, 128, 0, stream>>>(psum, psq, gamma, beta, scale, shift);
    k_bnpool<<<BN_BLOCKS, 256, 0, stream>>>(
        y16, gids, scale, shift, x_out, phis);
}